// Round 8
// baseline (336.906 us; speedup 1.0000x reference)
//
#include <hip/hip_runtime.h>
#include <hip/hip_bf16.h>

#define N_NODES 100000
#define N_EDGES 800000
#define N_GRAPHS 16
#define NFEAT 128
#define NHID 128
#define NCLASS 2

#define SCAN_CHUNK 2048
#define NCHUNK ((N_NODES + SCAN_CHUNK - 1) / SCAN_CHUNK)  // 49

#define SUM_ROWS 256
#define SUM_NB ((N_NODES + SUM_ROWS - 1) / SUM_ROWS)  // 391

#define GEMM_BLOCKS 512
#define N_CHUNKS (N_NODES / 16)  // 6250 exact

#define FILL_BINS 8
#define FILL_SLICES 128
#define FILL_BIN_W (N_NODES / FILL_BINS)        // 12500
#define FILL_SLICE_E (N_EDGES / FILL_SLICES)    // 6250

#define BIN_SLICES 64
#define BIN_SLICE_E (N_EDGES / BIN_SLICES)      // 12500

typedef unsigned int uint32;
typedef unsigned short ushort16;
typedef __attribute__((ext_vector_type(8))) short short8;
typedef __attribute__((ext_vector_type(4))) float f32x4;
typedef __attribute__((ext_vector_type(2))) float f32x2;

// ---- bf16 helpers (manual RNE; low ushort = first element of the pair) ----
__device__ __forceinline__ unsigned short f2bf(float f) {
  unsigned u = __float_as_uint(f);
  unsigned r = (u + 0x7fffu + ((u >> 16) & 1u)) >> 16;
  return (unsigned short)r;
}
__device__ __forceinline__ uint32 bfpack(float a, float b) {
  return (uint32)f2bf(a) | ((uint32)f2bf(b) << 16);
}
__device__ __forceinline__ float bflo(uint32 u) { return __uint_as_float(u << 16); }
__device__ __forceinline__ float bfhi(uint32 u) { return __uint_as_float(u & 0xffff0000u); }

// ---------------- utility ----------------
__global__ void k_zero(int* __restrict__ a) {
  int i = blockIdx.x * blockDim.x + threadIdx.x;
  if (i < N_NODES) a[i] = 0;
}

// XCD-binned in-degree: bin = blockIdx%8 handles targets in its 12500-node
// range only (single-XCD writer per deg line -> no cross-XCD line ping-pong,
// same fix as k_fill R6->R7). Edge targets re-read 8x = streaming, cheap.
__global__ __launch_bounds__(256) void k_deg(const int* __restrict__ ei,
                                             int* __restrict__ deg) {
  int bin = blockIdx.x & (FILL_BINS - 1);
  int slice = blockIdx.x >> 3;
  int lo = bin * FILL_BIN_W;
  int hi = lo + FILL_BIN_W;
  int e0 = slice * BIN_SLICE_E;
  int e1 = e0 + BIN_SLICE_E;
  for (int e = e0 + threadIdx.x; e < e1; e += 256) {
    int c = ei[N_EDGES + e];
    if (c >= lo && c < hi) atomicAdd(&deg[c], 1);
  }
}

// ---------------- scan of deg -> offsets (+ dinv fused) ----------------
__global__ void k_scan1(const int* __restrict__ deg, int* __restrict__ csum,
                        float* __restrict__ dinv) {
  __shared__ int lds[256];
  int b = blockIdx.x, t = threadIdx.x;
  int base = b * SCAN_CHUNK + t * 8;
  int s = 0;
#pragma unroll
  for (int k = 0; k < 8; ++k) {
    int i = base + k;
    int d = (i < N_NODES) ? deg[i] : 0;
    if (i < N_NODES) dinv[i] = rsqrtf((float)d + 1.0f);
    s += d;
  }
  lds[t] = s;
  __syncthreads();
  for (int off = 128; off > 0; off >>= 1) {
    if (t < off) lds[t] += lds[t + off];
    __syncthreads();
  }
  if (t == 0) csum[b] = lds[0];
}

// writes offsets AND cursor (cursor starts at offsets; k_fill atomics on it)
__global__ void k_scan3(const int* __restrict__ deg, const int* __restrict__ csum,
                        int* __restrict__ offsets, int* __restrict__ cursor) {
  __shared__ int lds[256];
  __shared__ int soff;
  int b = blockIdx.x, t = threadIdx.x;
  if (t == 0) {
    int run = 0;
    for (int i = 0; i < b; ++i) run += csum[i];
    soff = run;
  }
  int base = b * SCAN_CHUNK + t * 8;
  int v[8];
  int s = 0;
#pragma unroll
  for (int k = 0; k < 8; ++k) {
    int i = base + k;
    v[k] = (i < N_NODES) ? deg[i] : 0;
    s += v[k];
  }
  lds[t] = s;
  __syncthreads();
  int total = s;
  for (int off = 1; off < 256; off <<= 1) {
    int x = (t >= off) ? lds[t - off] : 0;
    __syncthreads();
    lds[t] += x;
    __syncthreads();
  }
  int run = lds[t] - total + soff;
#pragma unroll
  for (int k = 0; k < 8; ++k) {
    int i = base + k;
    if (i < N_NODES) { offsets[i] = run; cursor[i] = run; }
    run += v[k];
  }
}

// XCD-binned CSR fill (R7, kept)
__global__ __launch_bounds__(256) void k_fill(const int* __restrict__ ei,
                                              int* __restrict__ cursor,
                                              int* __restrict__ csr_row) {
  int bin = blockIdx.x & (FILL_BINS - 1);
  int slice = blockIdx.x >> 3;
  int lo = bin * FILL_BIN_W;
  int hi = lo + FILL_BIN_W;
  int e0 = slice * FILL_SLICE_E;
  int e1 = e0 + FILL_SLICE_E;
  for (int e = e0 + threadIdx.x; e < e1; e += 256) {
    int c = ei[N_EDGES + e];
    if (c >= lo && c < hi) {
      int r = ei[e];
      int p = atomicAdd(&cursor[c], 1);
      csr_row[p] = r;
    }
  }
}

// ------- xw' = (x @ W1) * dinv[row], fp8-e4m3 out, MFMA 16x16x32 -------
// fp8 storage halves conv1's random-gather bytes (R7: conv1 fabric-BW-bound,
// 106MB fetch @ 2.85TB/s). Error budget: e4m3 ~3% rel -> pooled logit err
// ~1e-3 << 1.6e-2 threshold.
__global__ __launch_bounds__(256, 2) void k_gemm_mfma(const float* __restrict__ x,
                                                      const float* __restrict__ W1,
                                                      const float* __restrict__ dinv,
                                                      unsigned char* __restrict__ xw8) {
  __shared__ __align__(16) unsigned short Wt[128 * 136];  // 34.8 KB
  int t = threadIdx.x;
  for (int i = t; i < 4096; i += 256) {
    float4 w4 = ((const float4*)W1)[i];
    int k = i >> 5;         // 0..127
    int n0 = (i & 31) * 4;  // 0..124
    Wt[(n0 + 0) * 136 + k] = f2bf(w4.x);
    Wt[(n0 + 1) * 136 + k] = f2bf(w4.y);
    Wt[(n0 + 2) * 136 + k] = f2bf(w4.z);
    Wt[(n0 + 3) * 136 + k] = f2bf(w4.w);
  }
  __syncthreads();

  int lane = t & 63;
  int c = lane & 15;     // col-in-tile; also row-in-chunk for the A fragment
  int quad = lane >> 4;  // 0..3
  short8 b[4][8];        // all B fragments, register-resident
#pragma unroll
  for (int kt = 0; kt < 4; ++kt)
#pragma unroll
    for (int nt = 0; nt < 8; ++nt)
      b[kt][nt] = *(const short8*)&Wt[(nt * 16 + c) * 136 + kt * 32 + quad * 8];

  int wave = blockIdx.x * 4 + (t >> 6);
  for (int chunk = wave; chunk < N_CHUNKS; chunk += GEMM_BLOCKS * 4) {
    const float* xr = x + (size_t)(chunk * 16 + c) * 128 + quad * 8;
    short8 a[4];
#pragma unroll
    for (int kt = 0; kt < 4; ++kt) {
      float4 f0 = *(const float4*)(xr + kt * 32);
      float4 f1 = *(const float4*)(xr + kt * 32 + 4);
      short8 v;
      v[0] = (short)f2bf(f0.x); v[1] = (short)f2bf(f0.y);
      v[2] = (short)f2bf(f0.z); v[3] = (short)f2bf(f0.w);
      v[4] = (short)f2bf(f1.x); v[5] = (short)f2bf(f1.y);
      v[6] = (short)f2bf(f1.z); v[7] = (short)f2bf(f1.w);
      a[kt] = v;
    }
    f32x4 acc[8];
#pragma unroll
    for (int nt = 0; nt < 8; ++nt) acc[nt] = (f32x4)(0.f);
#pragma unroll
    for (int kt = 0; kt < 4; ++kt)
#pragma unroll
      for (int nt = 0; nt < 8; ++nt)
        acc[nt] = __builtin_amdgcn_mfma_f32_16x16x32_bf16(a[kt], b[kt][nt], acc[nt], 0, 0, 0);

    int rbase = chunk * 16 + quad * 4;  // D row = quad*4 + reg
    float d0 = dinv[rbase + 0], d1 = dinv[rbase + 1];
    float d2 = dinv[rbase + 2], d3 = dinv[rbase + 3];
#pragma unroll
    for (int nt = 0; nt < 8; ++nt) {
      int cb = nt * 16 + c;
      float v0 = acc[nt][0] * d0, v1 = acc[nt][1] * d1;
      float v2 = acc[nt][2] * d2, v3 = acc[nt][3] * d3;
      int p01 = __builtin_amdgcn_cvt_pk_fp8_f32(v0, v1, 0, false);
      int p23 = __builtin_amdgcn_cvt_pk_fp8_f32(v2, v3, 0, false);
      xw8[(size_t)(rbase + 0) * 128 + cb] = (unsigned char)(p01 & 0xff);
      xw8[(size_t)(rbase + 1) * 128 + cb] = (unsigned char)((p01 >> 8) & 0xff);
      xw8[(size_t)(rbase + 2) * 128 + cb] = (unsigned char)(p23 & 0xff);
      xw8[(size_t)(rbase + 3) * 128 + cb] = (unsigned char)((p23 >> 8) & 0xff);
    }
  }
}

// ----- conv1: per-node CSR gather of fp8 xw', h = relu(dc*Σ + b1), bf16 out -----
// Wave = 1 node; 4 groups of 16 lanes each gather one full 128B row per uint2
// load (512B/instr). Group partials butterfly-reduced via shfl_xor(16,32).
__global__ __launch_bounds__(256) void k_conv1(const unsigned char* __restrict__ xw8,
                                               const int* __restrict__ csr_row,
                                               const int* __restrict__ offsets,
                                               const int* __restrict__ deg,
                                               const float* __restrict__ dinv,
                                               const float* __restrict__ b1,
                                               ushort16* __restrict__ h) {
  int lane = threadIdx.x & 63;
  int node = blockIdx.x * 4 + (threadIdx.x >> 6);
  if (node >= N_NODES) return;
  int grp = lane >> 4;  // 0..3: which row of the 4-row batch
  int j = lane & 15;    // feature block j*8..j*8+7
  float acc[8];
#pragma unroll
  for (int k = 0; k < 8; ++k) acc[k] = 0.f;
  int st = offsets[node], cnt = deg[node];
  const uint2* rowp = (const uint2*)xw8;  // fp8 row = 16 uint2
  // row idx 0 = self, 1..cnt = csr neighbors
#pragma unroll 2
  for (int s = 0; s <= cnt; s += 4) {
    int idx = s + grp;
    uint2 u = make_uint2(0u, 0u);
    if (idx <= cnt) {
      int r = (idx == 0) ? node : csr_row[st + idx - 1];
      u = rowp[(size_t)r * 16 + j];
    }
    f32x2 f0 = __builtin_amdgcn_cvt_pk_f32_fp8(u.x, false);
    f32x2 f1 = __builtin_amdgcn_cvt_pk_f32_fp8(u.x, true);
    f32x2 f2 = __builtin_amdgcn_cvt_pk_f32_fp8(u.y, false);
    f32x2 f3 = __builtin_amdgcn_cvt_pk_f32_fp8(u.y, true);
    acc[0] += f0[0]; acc[1] += f0[1]; acc[2] += f1[0]; acc[3] += f1[1];
    acc[4] += f2[0]; acc[5] += f2[1]; acc[6] += f3[0]; acc[7] += f3[1];
  }
#pragma unroll
  for (int k = 0; k < 8; ++k) {
    acc[k] += __shfl_xor(acc[k], 16, 64);
    acc[k] += __shfl_xor(acc[k], 32, 64);
  }
  float dc = dinv[node];
  float4 bA = *(const float4*)(b1 + j * 8);
  float4 bB = *(const float4*)(b1 + j * 8 + 4);
  if (grp == 0) {
    float o0 = fmaxf(acc[0] * dc + bA.x, 0.f);
    float o1 = fmaxf(acc[1] * dc + bA.y, 0.f);
    float o2 = fmaxf(acc[2] * dc + bA.z, 0.f);
    float o3 = fmaxf(acc[3] * dc + bA.w, 0.f);
    float o4 = fmaxf(acc[4] * dc + bB.x, 0.f);
    float o5 = fmaxf(acc[5] * dc + bB.y, 0.f);
    float o6 = fmaxf(acc[6] * dc + bB.z, 0.f);
    float o7 = fmaxf(acc[7] * dc + bB.w, 0.f);
    uint4 w;
    w.x = bfpack(o0, o1); w.y = bfpack(o2, o3);
    w.z = bfpack(o4, o5); w.w = bfpack(o6, o7);
    ((uint4*)h)[(size_t)node * 16 + j] = w;  // bf16 row = 16 uint4
  }
}

// ----- coef[r][g] = Σ_{e from r, batch[col]=g} dinv[r]dinv[c]  (+self) -----
__global__ void k_coef_init(const int* __restrict__ batch, const float* __restrict__ dinv,
                            float* __restrict__ coef) {
  int i = blockIdx.x * blockDim.x + threadIdx.x;  // node*16+g
  if (i < N_NODES * N_GRAPHS) {
    int n = i >> 4, g = i & 15;
    float d = dinv[n];
    coef[i] = (g == batch[n]) ? d * d : 0.f;
  }
}

// XCD-binned by source r (coef is indexed by r): single-XCD writer per line.
__global__ __launch_bounds__(256) void k_coef_edge(const int* __restrict__ ei,
                                                   const int* __restrict__ batch,
                                                   const float* __restrict__ dinv,
                                                   float* __restrict__ coef) {
  int bin = blockIdx.x & (FILL_BINS - 1);
  int slice = blockIdx.x >> 3;
  int lo = bin * FILL_BIN_W;
  int hi = lo + FILL_BIN_W;
  int e0 = slice * BIN_SLICE_E;
  int e1 = e0 + BIN_SLICE_E;
  for (int e = e0 + threadIdx.x; e < e1; e += 256) {
    int r = ei[e];
    if (r >= lo && r < hi) {
      int c = ei[N_EDGES + e];
      int g = batch[c];
      atomicAdd(&coef[r * N_GRAPHS + g], dinv[r] * dinv[c]);
    }
  }
}

// ----- s[g][f] = Σ_r coef[r][g]*h[r][f]  (streaming bf16 h; coef in LDS) -----
__global__ __launch_bounds__(256) void k_sum(const ushort16* __restrict__ h,
                                             const float* __restrict__ coef,
                                             float* __restrict__ partials) {
  __shared__ float lds[8192];  // phase1: coef tile (16KB); phase2: wave partials (32KB)
  int t = threadIdx.x;
  int base = blockIdx.x * SUM_ROWS;

  for (int i = t; i < SUM_ROWS * 16 / 4; i += 256) {
    int gidx = base * 16 / 4 + i;
    float4 v = (gidx * 4 < N_NODES * 16) ? ((const float4*)coef)[gidx]
                                         : make_float4(0.f, 0.f, 0.f, 0.f);
    ((float4*)lds)[i] = v;
  }
  __syncthreads();

  int lane = t & 63;
  int q = t >> 6;  // wave id 0..3
  float2 acc[16];
#pragma unroll
  for (int g = 0; g < 16; ++g) acc[g] = make_float2(0.f, 0.f);

  const uint32* h2 = (const uint32*)h;
  for (int k = 0; k < SUM_ROWS / 4; ++k) {
    int lr = q + 4 * k;
    int r = base + lr;
    uint32 u = (r < N_NODES) ? h2[(size_t)r * 64 + lane] : 0u;
    float hx = bflo(u), hy = bfhi(u);
    const float4* cb = (const float4*)&lds[lr * 16];
    float4 c0 = cb[0], c1 = cb[1], c2 = cb[2], c3 = cb[3];
    acc[0].x += c0.x * hx;  acc[0].y += c0.x * hy;
    acc[1].x += c0.y * hx;  acc[1].y += c0.y * hy;
    acc[2].x += c0.z * hx;  acc[2].y += c0.z * hy;
    acc[3].x += c0.w * hx;  acc[3].y += c0.w * hy;
    acc[4].x += c1.x * hx;  acc[4].y += c1.x * hy;
    acc[5].x += c1.y * hx;  acc[5].y += c1.y * hy;
    acc[6].x += c1.z * hx;  acc[6].y += c1.z * hy;
    acc[7].x += c1.w * hx;  acc[7].y += c1.w * hy;
    acc[8].x += c2.x * hx;  acc[8].y += c2.x * hy;
    acc[9].x += c2.y * hx;  acc[9].y += c2.y * hy;
    acc[10].x += c2.z * hx; acc[10].y += c2.z * hy;
    acc[11].x += c2.w * hx; acc[11].y += c2.w * hy;
    acc[12].x += c3.x * hx; acc[12].y += c3.x * hy;
    acc[13].x += c3.y * hx; acc[13].y += c3.y * hy;
    acc[14].x += c3.z * hx; acc[14].y += c3.z * hy;
    acc[15].x += c3.w * hx; acc[15].y += c3.w * hy;
  }
  __syncthreads();
  float2* red = (float2*)lds;
#pragma unroll
  for (int g = 0; g < 16; ++g) red[(q * 16 + g) * 64 + lane] = acc[g];
  __syncthreads();
#pragma unroll
  for (int ii = 0; ii < 4; ++ii) {
    int i = t + ii * 256;
    int g = i >> 6, fp = i & 63;
    float2 sv = red[(0 * 16 + g) * 64 + fp];
    float2 s1 = red[(1 * 16 + g) * 64 + fp];
    float2 s2 = red[(2 * 16 + g) * 64 + fp];
    float2 s3 = red[(3 * 16 + g) * 64 + fp];
    sv.x += s1.x + s2.x + s3.x;
    sv.y += s1.y + s2.y + s3.y;
    ((float2*)partials)[(size_t)blockIdx.x * 1024 + g * 64 + fp] = sv;
  }
}

__global__ void k_reduce(const float* __restrict__ partials, float* __restrict__ sglob) {
  int i = blockIdx.x * blockDim.x + threadIdx.x;
  if (i < N_GRAPHS * 128) {
    float s = 0.f;
    for (int b = 0; b < SUM_NB; ++b) s += partials[(size_t)b * (N_GRAPHS * 128) + i];
    sglob[i] = s;
  }
}

// ---------------- final: counts, s@W2, mean, log_softmax ----------------
__global__ void k_final(const float* __restrict__ sglob, const int* __restrict__ batch,
                        const float* __restrict__ W2, const float* __restrict__ b2,
                        float* __restrict__ out) {
  __shared__ int bnd[N_GRAPHS + 1];
  int t = threadIdx.x;
  if (t <= N_GRAPHS) {
    if (t == N_GRAPHS) {
      bnd[t] = N_NODES;
    } else if (t == 0) {
      bnd[t] = 0;
    } else {
      int lo = 0, hi = N_NODES;
      while (lo < hi) {
        int mid = (lo + hi) >> 1;
        if (batch[mid] < t) lo = mid + 1; else hi = mid;
      }
      bnd[t] = lo;
    }
  }
  __syncthreads();
  if (t < N_GRAPHS) {
    float cnt = fmaxf((float)(bnd[t + 1] - bnd[t]), 1.0f);
    float p0 = 0.f, p1 = 0.f;
    const float* sg = sglob + t * 128;
    for (int f = 0; f < 128; ++f) {
      float sv = sg[f];
      p0 += sv * W2[f * 2 + 0];
      p1 += sv * W2[f * 2 + 1];
    }
    p0 = p0 / cnt + b2[0];
    p1 = p1 / cnt + b2[1];
    float m = fmaxf(p0, p1);
    float lse = m + logf(expf(p0 - m) + expf(p1 - m));
    out[t * 2 + 0] = p0 - lse;
    out[t * 2 + 1] = p1 - lse;
  }
}

// ---------------- launch ----------------
static inline size_t align256(size_t x) { return (x + 255) & ~(size_t)255; }

extern "C" void kernel_launch(void* const* d_in, const int* in_sizes, int n_in,
                              void* d_out, int out_size, void* d_ws, size_t ws_size,
                              hipStream_t stream) {
  (void)in_sizes; (void)n_in; (void)out_size; (void)ws_size;
  const float* x  = (const float*)d_in[0];
  const int*   ei = (const int*)d_in[1];   // [2][E]
  const int*   batch = (const int*)d_in[2];
  const float* W1 = (const float*)d_in[3];
  const float* b1 = (const float*)d_in[4];
  const float* W2 = (const float*)d_in[5];
  const float* b2 = (const float*)d_in[6];
  float* out = (float*)d_out;

  char* w = (char*)d_ws;
  size_t off = 0;
  unsigned char* xw8 = (unsigned char*)(w + off); off = align256(off + (size_t)N_NODES * NHID);
  ushort16* h  = (ushort16*)(w + off);  off = align256(off + (size_t)N_NODES * NHID * 2);
  float* coef = (float*)(w + off);      off = align256(off + (size_t)N_NODES * N_GRAPHS * 4);
  int* csr_row = (int*)(w + off);       // alias with partials (partials used after conv1)
  float* partials = (float*)(w + off);
  size_t shared_sz = (size_t)SUM_NB * N_GRAPHS * 128 * 4;
  if ((size_t)N_EDGES * 4 > shared_sz) shared_sz = (size_t)N_EDGES * 4;
  off = align256(off + shared_sz);
  float* sglob = (float*)(w + off);     off = align256(off + (size_t)N_GRAPHS * 128 * 4);
  float* dinv = (float*)(w + off);      off = align256(off + (size_t)N_NODES * 4);
  int* deg = (int*)(w + off);           off = align256(off + (size_t)N_NODES * 4);
  int* cursor = (int*)(w + off);        off = align256(off + (size_t)N_NODES * 4);
  int* offsets = (int*)(w + off);       off = align256(off + (size_t)N_NODES * 4);
  int* csum = (int*)(w + off);          off = align256(off + (size_t)NCHUNK * 4);

  k_zero<<<(N_NODES + 255) / 256, 256, 0, stream>>>(deg);
  k_deg<<<FILL_BINS * BIN_SLICES, 256, 0, stream>>>(ei, deg);
  k_scan1<<<NCHUNK, 256, 0, stream>>>(deg, csum, dinv);
  k_scan3<<<NCHUNK, 256, 0, stream>>>(deg, csum, offsets, cursor);
  k_fill<<<FILL_BINS * FILL_SLICES, 256, 0, stream>>>(ei, cursor, csr_row);
  k_gemm_mfma<<<GEMM_BLOCKS, 256, 0, stream>>>(x, W1, dinv, xw8);
  k_conv1<<<(N_NODES + 3) / 4, 256, 0, stream>>>(xw8, csr_row, offsets, deg, dinv, b1, h);
  k_coef_init<<<(N_NODES * N_GRAPHS + 255) / 256, 256, 0, stream>>>(batch, dinv, coef);
  k_coef_edge<<<FILL_BINS * BIN_SLICES, 256, 0, stream>>>(ei, batch, dinv, coef);
  k_sum<<<SUM_NB, 256, 0, stream>>>(h, coef, partials);
  k_reduce<<<8, 256, 0, stream>>>(partials, sglob);
  k_final<<<1, 64, 0, stream>>>(sglob, batch, W2, b2, out);
}